// Round 7
// baseline (57.880 us; speedup 1.0000x reference)
//
#include <hip/hip_runtime.h>

// Fully-fused 4-layer MLP via f16 MFMA (fp32 accumulate), transposed problem
// G = H^T: activations live in registers across all layers (B operand).
// 8-wave (512-thread) blocks, 32 samples per wave (S=1, register-safe):
// 256 samples/block halves the redundant weight-staging L2 traffic vs R5 and
// gives exactly 2 resident blocks/CU (512 blocks total, no tail round).
// Weight strips 3-deep pipelined into LDS via global_load_lds with COUNTED
// vmcnt barriers (never vmcnt(0) in the main loop). L4 stores direct from C.

typedef _Float16 half_t;
typedef _Float16 half8 __attribute__((ext_vector_type(8)));
typedef float f32x16 __attribute__((ext_vector_type(16)));
typedef unsigned int uint4v __attribute__((ext_vector_type(4)));
typedef int int2v __attribute__((ext_vector_type(2)));

#define M_TOTAL (64*2048)

// ---------------- prep kernel ----------------
// Strip-ordered fragment layout (halves), 512 halves per fragment-block:
//   L1: blocks 0..7     (strip 0: all 8 nt, ks=0, K padded 13->16)
//   L2: blocks 8..135   (strips 1..8:  nt*16 + ks)
//   L3: blocks 136..263 (strips 9..16)
//   L4: blocks 264..311 (strips 17..19, N padded 80->96)
// Within a block: wp[blk*512 + lane*8 + j] = W[ks*16 + (lane>>5)*8 + j][nt*32 + (lane&31)]
__global__ void prep_w(const float* __restrict__ W1, const float* __restrict__ W2,
                       const float* __restrict__ W3, const float* __restrict__ W4,
                       half_t* __restrict__ wp) {
    int tid = blockIdx.x * 256 + threadIdx.x;
    if (tid >= 312 * 512) return;
    int blk = tid >> 9, r = tid & 511;
    int lane = r >> 3, j = r & 7;
    const float* W; int K, N, nt, ks;
    if (blk < 8)        { W = W1; K = 13;  N = 256; nt = blk;              ks = 0; }
    else if (blk < 136) { W = W2; K = 256; N = 256; nt = (blk-8) >> 4;     ks = (blk-8) & 15; }
    else if (blk < 264) { W = W3; K = 256; N = 256; nt = (blk-136) >> 4;   ks = (blk-136) & 15; }
    else                { W = W4; K = 256; N = 80;  nt = (blk-264) >> 4;   ks = (blk-264) & 15; }
    int k = ks * 16 + (lane >> 5) * 8 + j;
    int n = nt * 32 + (lane & 31);
    float v = (k < K && n < N) ? W[k * N + n] : 0.f;
    wp[tid] = (half_t)v;
}

// ---------------- main kernel ----------------

__device__ __forceinline__ unsigned int pkrtz(float a, float b) {
    auto p = __builtin_amdgcn_cvt_pkrtz(a, b);
    return __builtin_bit_cast(unsigned int, p);
}

typedef const __attribute__((address_space(1))) unsigned int guint_t;
typedef __attribute__((address_space(3))) unsigned int luint_t;

// Stage `bytes` (multiple of 8192) from g into LDS l. 512 threads x 16 B.
__device__ __forceinline__ void stage_strip(const half_t* __restrict__ g,
                                            half_t* l, int bytes, int tid) {
    const char* gc = (const char*)g;
    char* lc = (char*)l;
    const int go = tid * 16;             // per-lane global offset
    const int lo = (tid >> 6) << 10;     // wave-uniform LDS offset (wave*1024)
#pragma unroll
    for (int r = 0; r < bytes; r += 8192) {
        __builtin_amdgcn_global_load_lds((guint_t*)(gc + r + go),
                                         (luint_t*)(lc + r + lo), 16, 0, 0);
    }
}

// strip index -> offset in wp (halves); folds at compile time after unroll
__device__ __forceinline__ int strip_off(int s) {
    if (s == 0)  return 0;
    if (s <= 8)  return (8   + (s - 1)  * 16) * 512;
    if (s <= 16) return (136 + (s - 9)  * 16) * 512;
    return (264 + (s - 17) * 16) * 512;
}

// Counted-vmcnt pipeline barrier: keep newest stage's loads in flight.
#define PIPE_BAR(Nstr) do {                                   \
    asm volatile("s_waitcnt vmcnt(" Nstr ")" ::: "memory");   \
    __builtin_amdgcn_sched_barrier(0);                        \
    __builtin_amdgcn_s_barrier();                             \
    __builtin_amdgcn_sched_barrier(0);                        \
} while (0)

// One 32-feature output tile: K = NKS*16 from LDS strip, repack into 2 B-words.
template <int NKS, bool RELU>
__device__ __forceinline__ void dense_tile(const half_t* astrip,
                                           const unsigned int (&Bin)[16][4],
                                           unsigned int (*Bout)[4],
                                           const float* biasnt, int lane, bool hi)
{
    f32x16 acc = {};
#pragma unroll
    for (int ks = 0; ks < NKS; ++ks) {
        half8 a = *(const half8*)(astrip + ((ks * 64 + lane) << 3));
        uint4v bw = { Bin[ks][0], Bin[ks][1], Bin[ks][2], Bin[ks][3] };
        acc = __builtin_amdgcn_mfma_f32_32x32x16_f16(a, __builtin_bit_cast(half8, bw),
                                                     acc, 0, 0, 0);
    }
#pragma unroll
    for (int s = 0; s < 2; ++s) {
        float v[8];
#pragma unroll
        for (int q = 0; q < 8; ++q) {
            // C row = (reg&3) + 8*(reg>>2) + 4*(lane>=32), reg = 8s+q
            int f = (q & 3) + 8 * (q >> 2) + (hi ? 4 : 0);
            float t = acc[8 * s + q] + biasnt[16 * s + f];
            v[q] = RELU ? fmaxf(t, 0.f) : t;
        }
        unsigned int P0 = pkrtz(v[0], v[1]);   // lo:(0,1)  hi:(4,5)
        unsigned int P1 = pkrtz(v[2], v[3]);   // lo:(2,3)  hi:(6,7)
        unsigned int P2 = pkrtz(v[4], v[5]);   // lo:(8,9)  hi:(12,13)
        unsigned int P3 = pkrtz(v[6], v[7]);   // lo:(10,11) hi:(14,15)
        // One swap fills two B-words: word0=[P0.lo|P2.lo], word2=[P0.hi|P2.hi]
        int2v r02 = __builtin_amdgcn_permlane32_swap((int)P0, (int)P2, false, false);
        int2v r13 = __builtin_amdgcn_permlane32_swap((int)P1, (int)P3, false, false);
        Bout[s][0] = (unsigned int)r02.x;
        Bout[s][1] = (unsigned int)r13.x;
        Bout[s][2] = (unsigned int)r02.y;
        Bout[s][3] = (unsigned int)r13.y;
    }
}

// L4 tile: 32 features, direct global stores from the C fragment.
__device__ __forceinline__ void out_tile(const half_t* astrip,
                                         const unsigned int (&Bin)[16][4],
                                         const float* biasnt, float* __restrict__ out,
                                         int m0, int nt, int lane, bool hi)
{
    f32x16 acc = {};
#pragma unroll
    for (int ks = 0; ks < 16; ++ks) {
        half8 a = *(const half8*)(astrip + ((ks * 64 + lane) << 3));
        uint4v bw = { Bin[ks][0], Bin[ks][1], Bin[ks][2], Bin[ks][3] };
        acc = __builtin_amdgcn_mfma_f32_32x32x16_f16(a, __builtin_bit_cast(half8, bw),
                                                     acc, 0, 0, 0);
    }
    float* orow = out + (long)(m0 + (lane & 31)) * 80 + nt * 32;
#pragma unroll
    for (int reg = 0; reg < 16; ++reg) {
        if (nt == 2 && (reg >> 2) >= 2) continue;   // f = 64+rr < 80 <=> rr < 16
        int rr = (reg & 3) + 8 * (reg >> 2) + (hi ? 4 : 0);
        orow[rr] = acc[reg] + biasnt[rr];
    }
}

__global__ __launch_bounds__(512, 4) void mlp_mfma(
    const float* __restrict__ x, const half_t* __restrict__ wp,
    const float* __restrict__ b1, const float* __restrict__ b2,
    const float* __restrict__ b3, const float* __restrict__ b4,
    float* __restrict__ out)
{
    __shared__ half_t wbuf[3][8192];     // 3-deep strip pipeline (3 x 16 KB)
    __shared__ float  bias_lds[864];     // b1|b2|b3 (256 each) | b4 (96, padded)

    const int tid  = threadIdx.x;
    const int lane = tid & 63;
    const bool hi  = lane >= 32;
    const int m0   = (blockIdx.x * 8 + (tid >> 6)) * 32;   // 32 samples per wave

    if (tid < 256) {
        bias_lds[tid] = b1[tid];
        bias_lds[256 + tid] = b2[tid];
        bias_lds[512 + tid] = b3[tid];
    } else if (tid < 352) {
        int t = tid - 256;
        bias_lds[768 + t] = (t < 80) ? b4[t] : 0.f;
    }

    stage_strip(wp + strip_off(0), wbuf[0], 8192, tid);    // L1 strip (8 KB)
    stage_strip(wp + strip_off(1), wbuf[1], 16384, tid);

    unsigned int BA[16][4], BB[16][4];

    // Layer-1 B fragment from fp32 x: lane holds x[m][k], k = (hi?8:0)+j
    {
        const float* xp = x + (long)(m0 + (lane & 31)) * 13;
        float xv[8];
        if (!hi) {
#pragma unroll
            for (int j = 0; j < 8; ++j) xv[j] = xp[j];
        } else {
#pragma unroll
            for (int j = 0; j < 5; ++j) xv[j] = xp[8 + j];
            xv[5] = xv[6] = xv[7] = 0.f;
        }
        BA[0][0] = pkrtz(xv[0], xv[1]);
        BA[0][1] = pkrtz(xv[2], xv[3]);
        BA[0][2] = pkrtz(xv[4], xv[5]);
        BA[0][3] = pkrtz(xv[6], xv[7]);
    }

    __syncthreads();   // phase-0 entry: bias + strips 0,1 resident

    // ---- Phase 0 / L1: strip 0 (8 nt-blocks), 13->256 ----
    stage_strip(wp + strip_off(2), wbuf[2], 16384, tid);
#pragma unroll
    for (int nt = 0; nt < 8; ++nt)
        dense_tile<1, true>(&wbuf[0][nt * 512], BA, &BB[2 * nt],
                            bias_lds + nt * 32, lane, hi);

    // ---- Phases 1..8 / L2: strips 1..8, 256->256 ----
#pragma unroll
    for (int i = 0; i < 8; ++i) {
        const int k = 1 + i;
        PIPE_BAR("2");                              // strip k landed; k+1 in flight
        stage_strip(wp + strip_off(k + 2), wbuf[(k + 2) % 3], 16384, tid);
        dense_tile<16, true>(&wbuf[k % 3][0], BB, &BA[2 * i],
                             bias_lds + 256 + i * 32, lane, hi);
    }

    // ---- Phases 9..16 / L3: strips 9..16, 256->256 ----
#pragma unroll
    for (int i = 0; i < 8; ++i) {
        const int k = 9 + i;
        PIPE_BAR("2");
        stage_strip(wp + strip_off(k + 2), wbuf[(k + 2) % 3], 16384, tid);
        dense_tile<16, true>(&wbuf[k % 3][0], BA, &BB[2 * i],
                             bias_lds + 512 + i * 32, lane, hi);
    }

    // ---- Phases 17..19 / L4: strips 17..19, 256->80, direct stores ----
#pragma unroll
    for (int i = 0; i < 3; ++i) {
        const int k = 17 + i;
        if (i < 2) PIPE_BAR("2");                   // over-waits stores; safe
        else       PIPE_BAR("0");                   // last strip fully landed
        if (i == 0) stage_strip(wp + strip_off(19), wbuf[19 % 3], 16384, tid);
        out_tile(&wbuf[k % 3][0], BB, bias_lds + 768 + i * 32, out, m0, i, lane, hi);
    }
}

// ---------------- launch ----------------

extern "C" void kernel_launch(void* const* d_in, const int* in_sizes, int n_in,
                              void* d_out, int out_size, void* d_ws, size_t ws_size,
                              hipStream_t stream) {
    const float* x  = (const float*)d_in[0];
    const float* W1 = (const float*)d_in[1];
    const float* b1 = (const float*)d_in[2];
    const float* W2 = (const float*)d_in[3];
    const float* b2 = (const float*)d_in[4];
    const float* W3 = (const float*)d_in[5];
    const float* b3 = (const float*)d_in[6];
    const float* W4 = (const float*)d_in[7];
    const float* b4 = (const float*)d_in[8];
    float* out = (float*)d_out;

    half_t* wp = (half_t*)d_ws;

    hipLaunchKernelGGL(prep_w, dim3(624), dim3(256), 0, stream, W1, W2, W3, W4, wp);
    hipLaunchKernelGGL(mlp_mfma, dim3(M_TOTAL / 256), dim3(512), 0, stream,
                       x, wp, b1, b2, b3, b4, out);
}

// Round 8
// 55.091 us; speedup vs baseline: 1.0506x; 1.0506x over previous
//
#include <hip/hip_runtime.h>

// Fully-fused 4-layer MLP via f16 MFMA (fp32 accumulate), transposed problem
// G = H^T: activations live in registers across all layers (B operand).
// R8: 32 KB weight strips (2 nt-tiles per phase) -> 11 barrier phases instead
// of 20; 2-deep LDS double-buffer, stage issued at phase START (full-phase
// lead hides L2 latency, so plain __syncthreads suffices); s_setprio around
// MFMA clusters; grid 1024 = 2 clean generations at 2 blocks/CU.

typedef _Float16 half_t;
typedef _Float16 half8 __attribute__((ext_vector_type(8)));
typedef float f32x16 __attribute__((ext_vector_type(16)));
typedef unsigned int uint4v __attribute__((ext_vector_type(4)));
typedef int int2v __attribute__((ext_vector_type(2)));

#define M_TOTAL (64*2048)

// ---------------- prep kernel ----------------
// Fragment-block layout (512 halves per block), nt-major within each layer:
//   L1: blocks 0..7     (nt, ks=0; K padded 13->16)
//   L2: blocks 8..135   (nt*16 + ks)
//   L3: blocks 136..263 (nt*16 + ks)
//   L4: blocks 264..311 (nt*16 + ks; N padded 80->96)
// Within a block: wp[blk*512 + lane*8 + j] = W[ks*16 + (lane>>5)*8 + j][nt*32 + (lane&31)]
__global__ void prep_w(const float* __restrict__ W1, const float* __restrict__ W2,
                       const float* __restrict__ W3, const float* __restrict__ W4,
                       half_t* __restrict__ wp) {
    int tid = blockIdx.x * 256 + threadIdx.x;
    if (tid >= 312 * 512) return;
    int blk = tid >> 9, r = tid & 511;
    int lane = r >> 3, j = r & 7;
    const float* W; int K, N, nt, ks;
    if (blk < 8)        { W = W1; K = 13;  N = 256; nt = blk;              ks = 0; }
    else if (blk < 136) { W = W2; K = 256; N = 256; nt = (blk-8) >> 4;     ks = (blk-8) & 15; }
    else if (blk < 264) { W = W3; K = 256; N = 256; nt = (blk-136) >> 4;   ks = (blk-136) & 15; }
    else                { W = W4; K = 256; N = 80;  nt = (blk-264) >> 4;   ks = (blk-264) & 15; }
    int k = ks * 16 + (lane >> 5) * 8 + j;
    int n = nt * 32 + (lane & 31);
    float v = (k < K && n < N) ? W[k * N + n] : 0.f;
    wp[tid] = (half_t)v;
}

// ---------------- main kernel ----------------

__device__ __forceinline__ unsigned int pkrtz(float a, float b) {
    auto p = __builtin_amdgcn_cvt_pkrtz(a, b);
    return __builtin_bit_cast(unsigned int, p);
}

typedef const __attribute__((address_space(1))) unsigned int guint_t;
typedef __attribute__((address_space(3))) unsigned int luint_t;

// Stage `bytes` (multiple of 4096) from g into LDS l. 256 threads x 16 B.
__device__ __forceinline__ void stage_strip(const half_t* __restrict__ g,
                                            half_t* l, int bytes, int tid) {
    const char* gc = (const char*)g;
    char* lc = (char*)l;
    const int go = tid * 16;             // per-lane global offset
    const int lo = (tid >> 6) << 10;     // wave-uniform LDS offset (wave*1024)
#pragma unroll
    for (int r = 0; r < bytes; r += 4096) {
        __builtin_amdgcn_global_load_lds((guint_t*)(gc + r + go),
                                         (luint_t*)(lc + r + lo), 16, 0, 0);
    }
}

// strip index (0..10) -> offset in wp (halves). 0:L1 8KB; 1-4:L2; 5-8:L3;
// 9: L4 nt{0,1}; 10: L4 nt2 (16 KB).
__device__ __forceinline__ int strip_off(int s) {
    if (s == 0)  return 0;
    if (s <= 4)  return (8   + (s - 1) * 32) * 512;
    if (s <= 8)  return (136 + (s - 5) * 32) * 512;
    if (s == 9)  return 264 * 512;
    return 296 * 512;
}
__device__ __forceinline__ int strip_bytes(int s) {
    return (s == 0) ? 8192 : (s == 10 ? 16384 : 32768);
}

// One 32-feature output tile: K = NKS*16 from LDS, repack into 2 B-words.
template <int NKS, bool RELU>
__device__ __forceinline__ void dense_tile(const half_t* astrip,
                                           const unsigned int (&Bin)[16][4],
                                           unsigned int (*Bout)[4],
                                           const float* biasnt, int lane, bool hi)
{
    f32x16 acc = {};
    __builtin_amdgcn_s_setprio(1);
#pragma unroll
    for (int ks = 0; ks < NKS; ++ks) {
        half8 a = *(const half8*)(astrip + ((ks * 64 + lane) << 3));
        uint4v bw = { Bin[ks][0], Bin[ks][1], Bin[ks][2], Bin[ks][3] };
        acc = __builtin_amdgcn_mfma_f32_32x32x16_f16(a, __builtin_bit_cast(half8, bw),
                                                     acc, 0, 0, 0);
    }
    __builtin_amdgcn_s_setprio(0);
#pragma unroll
    for (int s = 0; s < 2; ++s) {
        float v[8];
#pragma unroll
        for (int q = 0; q < 8; ++q) {
            // C row = (reg&3) + 8*(reg>>2) + 4*(lane>=32), reg = 8s+q
            int f = (q & 3) + 8 * (q >> 2) + (hi ? 4 : 0);
            float t = acc[8 * s + q] + biasnt[16 * s + f];
            v[q] = RELU ? fmaxf(t, 0.f) : t;
        }
        unsigned int P0 = pkrtz(v[0], v[1]);   // lo:(0,1)  hi:(4,5)
        unsigned int P1 = pkrtz(v[2], v[3]);   // lo:(2,3)  hi:(6,7)
        unsigned int P2 = pkrtz(v[4], v[5]);   // lo:(8,9)  hi:(12,13)
        unsigned int P3 = pkrtz(v[6], v[7]);   // lo:(10,11) hi:(14,15)
        // One swap fills two B-words: word0=[P0.lo|P2.lo], word2=[P0.hi|P2.hi]
        int2v r02 = __builtin_amdgcn_permlane32_swap((int)P0, (int)P2, false, false);
        int2v r13 = __builtin_amdgcn_permlane32_swap((int)P1, (int)P3, false, false);
        Bout[s][0] = (unsigned int)r02.x;
        Bout[s][1] = (unsigned int)r13.x;
        Bout[s][2] = (unsigned int)r02.y;
        Bout[s][3] = (unsigned int)r13.y;
    }
}

// L4 tile: 32 features, direct global stores from the C fragment.
__device__ __forceinline__ void out_tile(const half_t* astrip,
                                         const unsigned int (&Bin)[16][4],
                                         const float* biasnt, float* __restrict__ out,
                                         int m0, int nt, int lane, bool hi)
{
    f32x16 acc = {};
    __builtin_amdgcn_s_setprio(1);
#pragma unroll
    for (int ks = 0; ks < 16; ++ks) {
        half8 a = *(const half8*)(astrip + ((ks * 64 + lane) << 3));
        uint4v bw = { Bin[ks][0], Bin[ks][1], Bin[ks][2], Bin[ks][3] };
        acc = __builtin_amdgcn_mfma_f32_32x32x16_f16(a, __builtin_bit_cast(half8, bw),
                                                     acc, 0, 0, 0);
    }
    __builtin_amdgcn_s_setprio(0);
    float* orow = out + (long)(m0 + (lane & 31)) * 80 + nt * 32;
#pragma unroll
    for (int reg = 0; reg < 16; ++reg) {
        if (nt == 2 && (reg >> 2) >= 2) continue;   // f = 64+rr < 80 <=> rr < 16
        int rr = (reg & 3) + 8 * (reg >> 2) + (hi ? 4 : 0);
        orow[rr] = acc[reg] + biasnt[rr];
    }
}

__global__ __launch_bounds__(256, 2) void mlp_mfma(
    const float* __restrict__ x, const half_t* __restrict__ wp,
    const float* __restrict__ b1, const float* __restrict__ b2,
    const float* __restrict__ b3, const float* __restrict__ b4,
    float* __restrict__ out)
{
    __shared__ half_t wbuf[2][16384];    // 2-deep strip pipeline (2 x 32 KB)
    __shared__ float  bias_lds[864];     // b1|b2|b3 (256 each) | b4 (96, padded)

    const int tid  = threadIdx.x;
    const int lane = tid & 63;
    const bool hi  = lane >= 32;
    const int m0   = (blockIdx.x * 4 + (tid >> 6)) * 32;   // 32 samples per wave

    stage_strip(wp + strip_off(0), wbuf[0], 8192, tid);    // L1 strip (8 KB)

    bias_lds[tid] = b1[tid];
    bias_lds[256 + tid] = b2[tid];
    bias_lds[512 + tid] = b3[tid];
    if (tid < 96) bias_lds[768 + tid] = (tid < 80) ? b4[tid] : 0.f;

    unsigned int BA[16][4], BB[16][4];

    // Layer-1 B fragment from fp32 x: lane holds x[m][k], k = (hi?8:0)+j
    {
        const float* xp = x + (long)(m0 + (lane & 31)) * 13;
        float xv[8];
        if (!hi) {
#pragma unroll
            for (int j = 0; j < 8; ++j) xv[j] = xp[j];
        } else {
#pragma unroll
            for (int j = 0; j < 5; ++j) xv[j] = xp[8 + j];
            xv[5] = xv[6] = xv[7] = 0.f;
        }
        BA[0][0] = pkrtz(xv[0], xv[1]);
        BA[0][1] = pkrtz(xv[2], xv[3]);
        BA[0][2] = pkrtz(xv[4], xv[5]);
        BA[0][3] = pkrtz(xv[6], xv[7]);
    }

    __syncthreads();   // strip 0 + bias resident

    // ---- Phase 0 / L1: strip 0 (8 nt-blocks, ks=0), 13->256 ----
    stage_strip(wp + strip_off(1), wbuf[1], 32768, tid);
    __builtin_amdgcn_sched_barrier(0);   // keep stage issue ahead of compute
#pragma unroll
    for (int nt = 0; nt < 8; ++nt)
        dense_tile<1, true>(&wbuf[0][nt * 512], BA, &BB[2 * nt],
                            bias_lds + nt * 32, lane, hi);
    __syncthreads();

    // ---- Phases 1..4 / L2: strips 1..4 (2 nt each), 256->256 ----
#pragma unroll
    for (int p = 1; p <= 4; ++p) {
        if (p < 10) {
            stage_strip(wp + strip_off(p + 1), wbuf[(p + 1) & 1], strip_bytes(p + 1), tid);
            __builtin_amdgcn_sched_barrier(0);
        }
        const half_t* sb = &wbuf[p & 1][0];
#pragma unroll
        for (int sub = 0; sub < 2; ++sub) {
            const int nt = (p - 1) * 2 + sub;
            dense_tile<16, true>(sb + sub * 16 * 512, BB, &BA[2 * nt],
                                 bias_lds + 256 + nt * 32, lane, hi);
        }
        __syncthreads();
    }

    // ---- Phases 5..8 / L3: strips 5..8, 256->256 ----
#pragma unroll
    for (int p = 5; p <= 8; ++p) {
        stage_strip(wp + strip_off(p + 1), wbuf[(p + 1) & 1], strip_bytes(p + 1), tid);
        __builtin_amdgcn_sched_barrier(0);
        const half_t* sb = &wbuf[p & 1][0];
#pragma unroll
        for (int sub = 0; sub < 2; ++sub) {
            const int nt = (p - 5) * 2 + sub;
            dense_tile<16, true>(sb + sub * 16 * 512, BA, &BB[2 * nt],
                                 bias_lds + 512 + nt * 32, lane, hi);
        }
        __syncthreads();
    }

    // ---- Phase 9 / L4 nt{0,1}: strip 9, 256->80 direct stores ----
    stage_strip(wp + strip_off(10), wbuf[0], 16384, tid);   // last strip -> buf0
    __builtin_amdgcn_sched_barrier(0);
#pragma unroll
    for (int sub = 0; sub < 2; ++sub)
        out_tile(&wbuf[1][sub * 16 * 512], BB, bias_lds + 768 + sub * 32,
                 out, m0, sub, lane, hi);
    __syncthreads();

    // ---- Phase 10 / L4 nt2 ----
    out_tile(&wbuf[0][0], BB, bias_lds + 768 + 64, out, m0, 2, lane, hi);
}

// ---------------- launch ----------------

extern "C" void kernel_launch(void* const* d_in, const int* in_sizes, int n_in,
                              void* d_out, int out_size, void* d_ws, size_t ws_size,
                              hipStream_t stream) {
    const float* x  = (const float*)d_in[0];
    const float* W1 = (const float*)d_in[1];
    const float* b1 = (const float*)d_in[2];
    const float* W2 = (const float*)d_in[3];
    const float* b2 = (const float*)d_in[4];
    const float* W3 = (const float*)d_in[5];
    const float* b3 = (const float*)d_in[6];
    const float* W4 = (const float*)d_in[7];
    const float* b4 = (const float*)d_in[8];
    float* out = (float*)d_out;

    half_t* wp = (half_t*)d_ws;

    hipLaunchKernelGGL(prep_w, dim3(624), dim3(256), 0, stream, W1, W2, W3, W4, wp);
    hipLaunchKernelGGL(mlp_mfma, dim3(M_TOTAL / 128), dim3(256), 0, stream,
                       x, wp, b1, b2, b3, b4, out);
}